// Round 2
// baseline (5536.324 us; speedup 1.0000x reference)
//
#include <hip/hip_runtime.h>

// 2-layer LSTM (NS=51), B=8192, T=2048, future=0.
// One block = 32 batch rows through all 2048 steps. 7 waves; wave w owns
// output-column tile w (32 cols) of the 204(+y) gate columns.
// mfma_f32_32x32x16_f16, weights stationary in VGPRs, state in swizzled LDS.
// Precision: h and x kept as fp16 hi+lo split (exact to ~2^-22), weights
// single-rounded fp16, fp32 MFMA accum, fp32 activations.

#define TLEN 2048
#define BTOT 8192
#define NSZ 51
#define NG 204            // 4*NS
#define NB 32             // batch rows per block
#define NTHREADS 448      // 7 waves
#define HS_STRIDE 512     // bytes per state row (swizzle-safe, 16B aligned)
#define ACT_STRIDE 208    // floats per act row

typedef _Float16 half8 __attribute__((ext_vector_type(8)));
typedef float f32x16 __attribute__((ext_vector_type(16)));

// State-row byte layout (fp16 elems): h1_hi [0,102) | h1_lo [102,204) |
// x_hi 204 | x_lo 206 | h2_hi [208,310) | h2_lo [310,412) | zero [412,512).
// Physical byte = row*512 + (logical_byte ^ ((row&7)<<4)); swizzle only
// touches bits 4-6 so 16B-aligned vector reads stay aligned and 2B writes
// stay consistent.
__device__ __forceinline__ int hs_off(int row, int lb) {
    return row * HS_STRIDE + (lb ^ ((row & 7) << 4));
}

__global__ __launch_bounds__(NTHREADS, 2) void lstm2_kernel(
    const float* __restrict__ xg,    // [B][T]
    const float* __restrict__ wih1,  // [204][1]
    const float* __restrict__ whh1,  // [204][51]
    const float* __restrict__ bih1, const float* __restrict__ bhh1,
    const float* __restrict__ wih2,  // [204][51]
    const float* __restrict__ whh2,  // [204][51]
    const float* __restrict__ bih2, const float* __restrict__ bhh2,
    const float* __restrict__ wlin,  // [51]
    const float* __restrict__ blin,  // [1]
    float* __restrict__ out)         // [B][T]
{
    __shared__ char  hs[NB * HS_STRIDE];     // 16 KB
    __shared__ float act[NB * ACT_STRIDE];   // 26.6 KB

    const int tid  = threadIdx.x;
    const int wave = tid >> 6;
    const int lane = tid & 63;
    const int nloc = lane & 31;
    const int h4   = lane >> 5;              // k-octet selector
    const int n    = wave * 32 + nloc;       // global output column 0..223
    const int b0   = blockIdx.x * NB;

    // zero state buffer (pad regions must stay 0 forever)
    for (int i = tid; i < NB * HS_STRIDE / 4; i += NTHREADS)
        ((int*)hs)[i] = 0;

    // ---- stationary weight fragments (fp16, registers) ----
    // B[k][col]: lane holds col = nloc, k = 16*s + 8*h4 + j.
    half8 B1[7];
#pragma unroll
    for (int s = 0; s < 7; ++s) {
        half8 v;
#pragma unroll
        for (int j = 0; j < 8; ++j) {
            const int k = 16 * s + 8 * h4 + j;
            float w = 0.0f;
            if (n < NG) {
                if (k < 51)        w = whh1[n * 51 + k];        // * h1_hi
                else if (k < 102)  w = whh1[n * 51 + (k - 51)]; // * h1_lo
                else if (k < 104)  w = wih1[n];                 // * x_hi, x_lo
            }
            v[j] = (_Float16)w;
        }
        B1[s] = v;
    }
    half8 B2[13];
#pragma unroll
    for (int s = 0; s < 13; ++s) {
        half8 v;
#pragma unroll
        for (int j = 0; j < 8; ++j) {
            const int k = 16 * s + 8 * h4 + j;
            float w = 0.0f;
            if (n < NG) {
                if (k < 51)                    w = wih2[n * 51 + k];
                else if (k < 102)              w = wih2[n * 51 + (k - 51)];
                else if (k >= 104 && k < 155)  w = whh2[n * 51 + (k - 104)];
                else if (k >= 155 && k < 206)  w = whh2[n * 51 + (k - 155)];
            } else if (n == NG) {              // y column: h2 . wlin = y_{t-1}
                if (k >= 104 && k < 155)       w = wlin[k - 104];
                else if (k >= 155 && k < 206)  w = wlin[k - 155];
            }
            v[j] = (_Float16)w;
        }
        B2[s] = v;
    }

    float bias1 = 0.0f, bias2 = 0.0f;
    if (n < NG) { bias1 = bih1[n] + bhh1[n]; bias2 = bih2[n] + bhh2[n]; }
    const float blin_v = blin[0];
    // unified sigmoid/tanh: r = rcp(1 + exp2(x*am)); result = as*r + ab
    const float LOG2E = 1.4426950408889634f;
    const bool  isg = (n < NG) && ((n / 51) == 2);
    const float am = isg ? (-2.0f * LOG2E) : (-LOG2E);
    const float as = isg ? 2.0f : 1.0f;
    const float ab = isg ? -1.0f : 0.0f;

    // C/D fragment row mapping (m74/m101): row=(q&3)+8*(q>>2)+4*(lane>>5)
    int crow[16];
#pragma unroll
    for (int q = 0; q < 16; ++q) crow[q] = (q & 3) + 8 * (q >> 2) + 4 * h4;

    // state-update task mapping: tau -> (b,u); c-states live in registers
    int tb[4], tu[4]; bool tact[4];
#pragma unroll
    for (int i = 0; i < 4; ++i) {
        const int tau = tid + i * NTHREADS;
        tact[i] = (tau < NB * NSZ);
        const int bb = tau / NSZ;
        tb[i] = bb; tu[i] = tau - bb * NSZ;
    }
    float c1[4] = {0, 0, 0, 0}, c2[4] = {0, 0, 0, 0};

    __syncthreads();
    // stage x_0
#pragma unroll
    for (int i = 0; i < 4; ++i) {
        if (tact[i] && tu[i] == 0) {
            const float xv = xg[(size_t)(b0 + tb[i]) * TLEN];
            const _Float16 xh = (_Float16)xv;
            const _Float16 xl = (_Float16)(xv - (float)xh);
            *(_Float16*)(hs + hs_off(tb[i], 204)) = xh;
            *(_Float16*)(hs + hs_off(tb[i], 206)) = xl;
        }
    }
    __syncthreads();

    const int arow = nloc;   // A-fragment row = lane&31

    for (int t = 0; t < TLEN; ++t) {
        // prefetch x_{t+1} (L1-resident: same 64B line for 16 steps)
        float xn[4];
#pragma unroll
        for (int i = 0; i < 4; ++i) {
            xn[i] = 0.0f;
            if (tact[i] && tu[i] == 0 && t + 1 < TLEN)
                xn[i] = xg[(size_t)(b0 + tb[i]) * TLEN + t + 1];
        }

        // ---- GEMM1: gates1 = [h1_hi|h1_lo|x_hi|x_lo] @ B1 (+bias) ----
        f32x16 acc;
#pragma unroll
        for (int q = 0; q < 16; ++q) acc[q] = bias1;
#pragma unroll
        for (int s = 0; s < 7; ++s) {
            const half8 a = *(const half8*)(hs + hs_off(arow, 32 * s + 16 * h4));
            acc = __builtin_amdgcn_mfma_f32_32x32x16_f16(a, B1[s], acc, 0, 0, 0);
        }
        if (n < NG) {
#pragma unroll
            for (int q = 0; q < 16; ++q) {
                const float e = __builtin_amdgcn_exp2f(acc[q] * am);
                const float r = __builtin_amdgcn_rcpf(1.0f + e);
                act[crow[q] * ACT_STRIDE + n] = as * r + ab;
            }
        }
        __syncthreads();

        // ---- layer-1 state update -> write h1 split into hs ----
#pragma unroll
        for (int i = 0; i < 4; ++i) {
            if (tact[i]) {
                const int b = tb[i], u = tu[i];
                const float gi = act[b * ACT_STRIDE + u];
                const float gf = act[b * ACT_STRIDE + 51 + u];
                const float gg = act[b * ACT_STRIDE + 102 + u];
                const float go = act[b * ACT_STRIDE + 153 + u];
                const float c = fmaf(gf, c1[i], gi * gg);
                c1[i] = c;
                const float e = __builtin_amdgcn_exp2f(c * (-2.0f * LOG2E));
                const float th = 2.0f * __builtin_amdgcn_rcpf(1.0f + e) - 1.0f;
                const float h = go * th;
                const _Float16 hh = (_Float16)h;
                const _Float16 hl = (_Float16)(h - (float)hh);
                *(_Float16*)(hs + hs_off(b, 2 * u)) = hh;
                *(_Float16*)(hs + hs_off(b, 102 + 2 * u)) = hl;
            }
        }
        __syncthreads();

        // ---- GEMM2: gates2 = [h1new|x|h2old] @ B2 (+bias); col 204 = y_{t-1} ----
#pragma unroll
        for (int q = 0; q < 16; ++q) acc[q] = bias2;
#pragma unroll
        for (int s = 0; s < 13; ++s) {
            const half8 a = *(const half8*)(hs + hs_off(arow, 32 * s + 16 * h4));
            acc = __builtin_amdgcn_mfma_f32_32x32x16_f16(a, B2[s], acc, 0, 0, 0);
        }
        if (n < NG) {
#pragma unroll
            for (int q = 0; q < 16; ++q) {
                const float e = __builtin_amdgcn_exp2f(acc[q] * am);
                const float r = __builtin_amdgcn_rcpf(1.0f + e);
                act[crow[q] * ACT_STRIDE + n] = as * r + ab;
            }
        } else if (n == NG && t > 0) {
#pragma unroll
            for (int q = 0; q < 16; ++q)
                out[(size_t)(b0 + crow[q]) * TLEN + (t - 1)] = acc[q] + blin_v;
        }
        __syncthreads();

        // ---- layer-2 state update + stage x_{t+1} ----
#pragma unroll
        for (int i = 0; i < 4; ++i) {
            if (tact[i]) {
                const int b = tb[i], u = tu[i];
                const float gi = act[b * ACT_STRIDE + u];
                const float gf = act[b * ACT_STRIDE + 51 + u];
                const float gg = act[b * ACT_STRIDE + 102 + u];
                const float go = act[b * ACT_STRIDE + 153 + u];
                const float c = fmaf(gf, c2[i], gi * gg);
                c2[i] = c;
                const float e = __builtin_amdgcn_exp2f(c * (-2.0f * LOG2E));
                const float th = 2.0f * __builtin_amdgcn_rcpf(1.0f + e) - 1.0f;
                const float h = go * th;
                const _Float16 hh = (_Float16)h;
                const _Float16 hl = (_Float16)(h - (float)hh);
                *(_Float16*)(hs + hs_off(b, 208 + 2 * u)) = hh;
                *(_Float16*)(hs + hs_off(b, 310 + 2 * u)) = hl;
                if (tu[i] == 0 && t + 1 < TLEN) {
                    const _Float16 xh = (_Float16)xn[i];
                    const _Float16 xl = (_Float16)(xn[i] - (float)xh);
                    *(_Float16*)(hs + hs_off(b, 204)) = xh;
                    *(_Float16*)(hs + hs_off(b, 206)) = xl;
                }
            }
        }
        __syncthreads();
    }

    // ---- final output column y_{T-1} = wlin . h2_final + blin (fp32) ----
#pragma unroll
    for (int i = 0; i < 4; ++i) {
        if (tact[i]) {
            const int b = tb[i], u = tu[i];
            const float hh = (float)*(const _Float16*)(hs + hs_off(b, 208 + 2 * u));
            const float hl = (float)*(const _Float16*)(hs + hs_off(b, 310 + 2 * u));
            act[b * ACT_STRIDE + u] = wlin[u] * (hh + hl);
        }
    }
    __syncthreads();
    if (tid < NB) {
        float s = blin_v;
        for (int u = 0; u < NSZ; ++u) s += act[tid * ACT_STRIDE + u];
        out[(size_t)(b0 + tid) * TLEN + (TLEN - 1)] = s;
    }
}

extern "C" void kernel_launch(void* const* d_in, const int* in_sizes, int n_in,
                              void* d_out, int out_size, void* d_ws, size_t ws_size,
                              hipStream_t stream) {
    (void)in_sizes; (void)n_in; (void)d_ws; (void)ws_size; (void)out_size;
    const float* xg   = (const float*)d_in[0];
    const float* wih1 = (const float*)d_in[1];
    const float* whh1 = (const float*)d_in[2];
    const float* bih1 = (const float*)d_in[3];
    const float* bhh1 = (const float*)d_in[4];
    const float* wih2 = (const float*)d_in[5];
    const float* whh2 = (const float*)d_in[6];
    const float* bih2 = (const float*)d_in[7];
    const float* bhh2 = (const float*)d_in[8];
    const float* wlin = (const float*)d_in[9];
    const float* blin = (const float*)d_in[10];
    // d_in[11] = future (static 0) -- ignored
    lstm2_kernel<<<dim3(BTOT / NB), dim3(NTHREADS), 0, stream>>>(
        xg, wih1, whh1, bih1, bhh1, wih2, whh2, bih2, bhh2, wlin, blin,
        (float*)d_out);
}

// Round 3
// 4015.648 us; speedup vs baseline: 1.3787x; 1.3787x over previous
//
#include <hip/hip_runtime.h>

// 2-layer LSTM (NS=51), B=8192, T=2048, future=0.
// Operand-swapped MFMA: A = weights (stationary VGPR fragments, M = gate rows
// interleaved as 4u+g), B = state (LDS, N = 32 batch rows). C-fragment then
// hands each lane all 4 gates of its (b,u) tasks -> in-register LSTM update,
// no act[] round-trip. Double-buffered state, 2 barriers/step.
// Precision: h,x as fp16 hi+lo pairs (duplicated weights), weights fp16 with
// gate log2e-scale folded in, fp32 MFMA accum, fp32 activations.

#define TLEN 2048
#define BTOT 8192
#define NSZ  51
#define NB   32
#define NTHREADS 448       // 7 waves
#define ROWB 512           // bytes per state row
#define BUFB (NB * ROWB)   // 16 KB per buffer

// Row k-layout (fp16 index k, byte = 2k):
//  k[0,102)   h1 pairs (u = k>>1; hi at even k, lo at odd k)
//  k[102,104) x pair
//  k[104,112) pad (zero weights)
//  k[112,214) h2 pairs (u = (k-112)>>1)
//  k[214,256) pad (zero data + zero weights)
// GEMM1 reads k[0,112) (7 k-steps); GEMM2 reads k[0,224) (14 k-steps).

typedef _Float16 half8 __attribute__((ext_vector_type(8)));
typedef float f32x16 __attribute__((ext_vector_type(16)));

__device__ __forceinline__ int swz_off(int row, int byte) {
    return row * ROWB + (byte ^ ((row & 7) << 4));
}

#define UPDATE_LAYER(ACC, CST, BASE, BOFF)                                     \
  _Pragma("unroll")                                                            \
  for (int m = 0; m < 4; ++m) {                                                \
    const float gi = __builtin_amdgcn_rcpf(1.0f + __builtin_amdgcn_exp2f((ACC)[4*m+0])); \
    const float gf = __builtin_amdgcn_rcpf(1.0f + __builtin_amdgcn_exp2f((ACC)[4*m+1])); \
    const float gt = fmaf(2.0f, __builtin_amdgcn_rcpf(1.0f + __builtin_amdgcn_exp2f((ACC)[4*m+2])), -1.0f); \
    const float go = __builtin_amdgcn_rcpf(1.0f + __builtin_amdgcn_exp2f((ACC)[4*m+3])); \
    const float cn = fmaf(gf, (CST)[m], gi * gt);                              \
    (CST)[m] = cn;                                                             \
    const float ee = __builtin_amdgcn_exp2f(-2.8853900817779268f * cn);        \
    const float th = fmaf(2.0f, __builtin_amdgcn_rcpf(1.0f + ee), -1.0f);      \
    const float hv = go * th;                                                  \
    const int u = 8 * wv + 2 * m + h4;                                         \
    if (u < NSZ) {                                                             \
      const _Float16 hh = (_Float16)hv;                                        \
      const _Float16 hl = (_Float16)(hv - (float)hh);                          \
      const unsigned pk = (unsigned)__builtin_bit_cast(unsigned short, hh)     \
                        | ((unsigned)__builtin_bit_cast(unsigned short, hl) << 16); \
      *(unsigned*)((BASE) + swz_off(nloc, (BOFF) + 4 * u)) = pk;               \
    }                                                                          \
  }

__global__ __launch_bounds__(NTHREADS, 2) void lstm2_kernel(
    const float* __restrict__ xg,    // [B][T]
    const float* __restrict__ wih1,  // [204][1]
    const float* __restrict__ whh1,  // [204][51]
    const float* __restrict__ bih1, const float* __restrict__ bhh1,
    const float* __restrict__ wih2,  // [204][51]
    const float* __restrict__ whh2,  // [204][51]
    const float* __restrict__ bih2, const float* __restrict__ bhh2,
    const float* __restrict__ wlin,  // [51]
    const float* __restrict__ blin,  // [1]
    float* __restrict__ out)         // [B][T]
{
    __shared__ char hs[2 * BUFB];    // 32 KB, ping-pong state buffers

    const int tid  = threadIdx.x;
    const int wv   = tid >> 6;       // wave = M-tile (gate-row tile)
    const int lane = tid & 63;
    const int nloc = lane & 31;      // batch column b (C/D col) and state row
    const int h4   = lane >> 5;      // k-octet selector
    const int b0   = blockIdx.x * NB;

    // zero both state buffers (pads must stay 0)
    for (int i = tid; i < 2 * BUFB / 4; i += NTHREADS) ((int*)hs)[i] = 0;

    const float LOG2E = 1.4426950408889634f;
    const int n = wv * 32 + nloc;    // interleaved gate-row this lane supplies
    const int Rrow = (n < 204) ? 51 * (n & 3) + (n >> 2) : 0;  // PyTorch row
    const float am = (n < 204) ? (((n & 3) == 2) ? (-2.0f * LOG2E) : (-LOG2E))
                               : 1.0f;

    // ---- stationary weight A-fragments (fp16, am-folded) ----
    half8 A1[7];
#pragma unroll
    for (int s = 0; s < 7; ++s) {
        half8 v;
#pragma unroll
        for (int j = 0; j < 8; ++j) {
            const int k = 16 * s + 8 * h4 + j;
            float w = 0.0f;
            if (n < 204) {
                if (k < 102)      w = am * whh1[Rrow * 51 + (k >> 1)];
                else if (k < 104) w = am * wih1[Rrow];
            }
            v[j] = (_Float16)w;
        }
        A1[s] = v;
    }
    half8 A2[14];
#pragma unroll
    for (int s = 0; s < 14; ++s) {
        half8 v;
#pragma unroll
        for (int j = 0; j < 8; ++j) {
            const int k = 16 * s + 8 * h4 + j;
            float w = 0.0f;
            if (n < 204) {
                if (k < 102)                  w = am * wih2[Rrow * 51 + (k >> 1)];
                else if (k >= 112 && k < 214) w = am * whh2[Rrow * 51 + ((k - 112) >> 1)];
            } else if (n == 204) {            // y row: wlin . h2 (am = 1)
                if (k >= 112 && k < 214)      w = wlin[(k - 112) >> 1];
            }
            v[j] = (_Float16)w;
        }
        A2[s] = v;
    }

    // ---- bias C-fragments (am-folded, f32) ----
    f32x16 b1v, b2v;
#pragma unroll
    for (int q = 0; q < 16; ++q) {
        const int rl = (q & 3) + 8 * (q >> 2) + 4 * h4;  // local C/D row
        const int nq = wv * 32 + rl;
        float v1 = 0.0f, v2 = 0.0f;
        if (nq < 204) {
            const int Rq = 51 * (nq & 3) + (nq >> 2);
            const float amq = ((nq & 3) == 2) ? (-2.0f * LOG2E) : (-LOG2E);
            v1 = amq * (bih1[Rq] + bhh1[Rq]);
            v2 = amq * (bih2[Rq] + bhh2[Rq]);
        } else if (nq == 204) {
            v2 = blin[0];
        }
        b1v[q] = v1; b2v[q] = v2;
    }

    float c1[4] = {0, 0, 0, 0}, c2[4] = {0, 0, 0, 0};

    __syncthreads();                 // zero-init visible
    // stage x_0 into S[0]
    if (tid < NB) {
        const float xv = xg[(size_t)(b0 + tid) * TLEN];
        const _Float16 xh = (_Float16)xv;
        const _Float16 xl = (_Float16)(xv - (float)xh);
        const unsigned pk = (unsigned)__builtin_bit_cast(unsigned short, xh)
                          | ((unsigned)__builtin_bit_cast(unsigned short, xl) << 16);
        *(unsigned*)(hs + swz_off(tid, 204)) = pk;
    }
    __syncthreads();

    for (int t = 0; t < TLEN; ++t) {
        const int p = t & 1;
        char* Sp = hs + p * BUFB;        // holds h1_{t-1}, x_t, h2_t(dst)
        char* Sq = hs + (p ^ 1) * BUFB;  // holds h2_{t-1}; h1_t, x_{t+1}(dst)

        // early x_{t+1} load (wave 6, h4==0 lanes own batch b = nloc)
        float xn = 0.0f;
        if (wv == 6 && h4 == 0 && t + 1 < TLEN)
            xn = xg[(size_t)(b0 + nloc) * TLEN + t + 1];

        // prefetch GEMM2's h2-half B-fragments from Sq (stable this phase)
        half8 bh2[7];
#pragma unroll
        for (int s = 0; s < 7; ++s)
            bh2[s] = *(const half8*)(Sq + swz_off(nloc, 224 + 32 * s + 16 * h4));

        // ---- GEMM1: gates1[rows 32wv..+31][b] over k[0,112) of Sp ----
        f32x16 acc = b1v;
#pragma unroll
        for (int s = 0; s < 7; ++s) {
            const half8 bfr = *(const half8*)(Sp + swz_off(nloc, 32 * s + 16 * h4));
            acc = __builtin_amdgcn_mfma_f32_32x32x16_f16(A1[s], bfr, acc, 0, 0, 0);
        }
        // ---- layer-1 update (in-register) -> h1_t into Sq k[0,102) ----
        UPDATE_LAYER(acc, c1, Sq, 0)
        __syncthreads();

        // ---- GEMM2: k[0,112) = h1_t from Sq, k[112,224) = h2_{t-1} ----
        f32x16 acc2 = b2v;
#pragma unroll
        for (int s = 0; s < 7; ++s) {
            const half8 bfr = *(const half8*)(Sq + swz_off(nloc, 32 * s + 16 * h4));
            acc2 = __builtin_amdgcn_mfma_f32_32x32x16_f16(A2[s], bfr, acc2, 0, 0, 0);
        }
#pragma unroll
        for (int s = 0; s < 7; ++s)
            acc2 = __builtin_amdgcn_mfma_f32_32x32x16_f16(A2[7 + s], bh2[s], acc2, 0, 0, 0);

        // y row (204) lives at q=4 of wave 6, h4==1: acc2[4] = wlin.h2_{t-1}+blin
        if (wv == 6 && h4 == 1 && t > 0)
            out[(size_t)(b0 + nloc) * TLEN + (t - 1)] = acc2[4];

        // ---- layer-2 update -> h2_t into Sp k[112,214); x_{t+1} -> Sq ----
        UPDATE_LAYER(acc2, c2, Sp, 224)
        if (wv == 6 && h4 == 0 && t + 1 < TLEN) {
            const _Float16 xh = (_Float16)xn;
            const _Float16 xl = (_Float16)(xn - (float)xh);
            const unsigned pk = (unsigned)__builtin_bit_cast(unsigned short, xh)
                              | ((unsigned)__builtin_bit_cast(unsigned short, xl) << 16);
            *(unsigned*)(Sq + swz_off(nloc, 204)) = pk;
        }
        __syncthreads();
    }

    // ---- final y_{T-1} = blin + wlin . h2_{T-1}; h2_{2047} sits in S[1] ----
    if (tid < NB) {
        const char* S1 = hs + BUFB;
        float s = blin[0];
        for (int u = 0; u < NSZ; ++u) {
            const unsigned pk = *(const unsigned*)(S1 + swz_off(tid, 224 + 4 * u));
            const float hh = (float)__builtin_bit_cast(_Float16, (unsigned short)(pk & 0xffffu));
            const float hl = (float)__builtin_bit_cast(_Float16, (unsigned short)(pk >> 16));
            s = fmaf(wlin[u], hh + hl, s);
        }
        out[(size_t)(b0 + tid) * TLEN + (TLEN - 1)] = s;
    }
}

extern "C" void kernel_launch(void* const* d_in, const int* in_sizes, int n_in,
                              void* d_out, int out_size, void* d_ws, size_t ws_size,
                              hipStream_t stream) {
    (void)in_sizes; (void)n_in; (void)d_ws; (void)ws_size; (void)out_size;
    const float* xg   = (const float*)d_in[0];
    const float* wih1 = (const float*)d_in[1];
    const float* whh1 = (const float*)d_in[2];
    const float* bih1 = (const float*)d_in[3];
    const float* bhh1 = (const float*)d_in[4];
    const float* wih2 = (const float*)d_in[5];
    const float* whh2 = (const float*)d_in[6];
    const float* bih2 = (const float*)d_in[7];
    const float* bhh2 = (const float*)d_in[8];
    const float* wlin = (const float*)d_in[9];
    const float* blin = (const float*)d_in[10];
    // d_in[11] = future (static 0) -- ignored
    lstm2_kernel<<<dim3(BTOT / NB), dim3(NTHREADS), 0, stream>>>(
        xg, wih1, whh1, bih1, bhh1, wih2, whh2, bih2, bhh2, wlin, blin,
        (float*)d_out);
}